// Round 3
// baseline (1068.922 us; speedup 1.0000x reference)
//
#include <hip/hip_runtime.h>
#include <hip/hip_bf16.h>
#include <cmath>

#define N0 50000
#define NEDGE 800000
#define NEG_HUGE -3.402823466e38f

// ---------- helpers ----------
__device__ inline unsigned fkey(float f) {
    unsigned b = __float_as_uint(f);
    if (b == 0x80000000u) b = 0u;  // canonicalize -0 -> +0
    return (b & 0x80000000u) ? ~b : (b | 0x80000000u);
}

__device__ inline void atomicMaxF(float* a, float v) {
    if (v >= 0.f) atomicMax((int*)a, __float_as_int(v));
    else          atomicMin((unsigned int*)a, __float_as_uint(v));
}

__device__ inline int waveInclScan(int v, int lane) {
#pragma unroll
    for (int off = 1; off < 64; off <<= 1) {
        int t = __shfl_up(v, off);
        if (lane >= off) v += t;
    }
    return v;
}

// ---------- kernels ----------
__global__ void k_init(const int* __restrict__ src, const int* __restrict__ dst,
                       int* cur_src, int* cur_dst, float* finalv, float* f1raw) {
    int i = blockIdx.x * blockDim.x + threadIdx.x;
    if (i < NEDGE) { cur_src[i] = src[i]; cur_dst[i] = dst[i]; }
    if (i < 256) { finalv[i] = 0.f; f1raw[i] = 0.f; }
}

__global__ void k_zero(int* deg_in, int* deg_out, int* fill, int n) {
    int i = blockIdx.x * blockDim.x + threadIdx.x;
    if (i < n) { deg_in[i] = 0; deg_out[i] = 0; fill[i] = 0; }
}

__global__ void k_hist(const int* __restrict__ cs, const int* __restrict__ cd,
                       int* deg_in, int* deg_out) {
    int e = blockIdx.x * blockDim.x + threadIdx.x;
    if (e >= NEDGE) return;
    int s = cs[e];
    if (s < 0) return;
    atomicAdd(&deg_out[s], 1);
    atomicAdd(&deg_in[cd[e]], 1);
}

__global__ void k_norms(const int* __restrict__ deg_in, const int* __restrict__ deg_out,
                        float* nsv, float* ndv, int n) {
    int i = blockIdx.x * blockDim.x + threadIdx.x;
    if (i >= n) return;
    nsv[i] = rsqrtf(fmaxf((float)deg_out[i], 1.f));
    ndv[i] = rsqrtf(fmaxf((float)deg_in[i], 1.f));
}

__global__ void k_scan(const int* __restrict__ deg, int* ptr, int n) {
    __shared__ int wsum[16];
    __shared__ int scarry, stot;
    int tid = threadIdx.x, lane = tid & 63, wid = tid >> 6;
    if (tid == 0) scarry = 0;
    __syncthreads();
    for (int base = 0; base < n; base += 1024) {
        int i = base + tid;
        int v = (i < n) ? deg[i] : 0;
        int inc = waveInclScan(v, lane);
        if (lane == 63) wsum[wid] = inc;
        __syncthreads();
        if (tid == 0) {
            int run = 0;
            for (int w = 0; w < 16; ++w) { int t2 = wsum[w]; wsum[w] = run; run += t2; }
            stot = run;
        }
        __syncthreads();
        int excl = scarry + wsum[wid] + inc - v;
        if (i < n) ptr[i] = excl;
        if (i == n - 1) ptr[n] = excl + v;
        __syncthreads();
        if (tid == 0) scarry += stot;
        __syncthreads();
    }
}

__global__ void k_fill(const int* __restrict__ cs, const int* __restrict__ cd,
                       const int* __restrict__ ptr, int* fill, int* csr_src) {
    int e = blockIdx.x * blockDim.x + threadIdx.x;
    if (e >= NEDGE) return;
    int s = cs[e];
    if (s < 0) return;
    int d = cd[e];
    int pos = atomicAdd(&fill[d], 1);
    csr_src[ptr[d] + pos] = s;
}

// h_pre = X @ W (all fp32).  mode 0: X = feat.  mode 1: X[r] = xprev[oldid[r]] * garr[r].
__global__ __launch_bounds__(256) void k_gemm(
        const float* __restrict__ feat, const float* __restrict__ xprev,
        const int* __restrict__ oldid, const float* __restrict__ garr,
        const float* __restrict__ W, float* __restrict__ hpre, int n, int mode) {
    __shared__ float Wt[32][132];
    __shared__ float Xt[64][33];
    int tid = threadIdx.x;
    int r0 = blockIdx.x * 64;
    int c0 = (tid & 7) * 16;
    int rl0 = (tid >> 3) * 2;
    float acc0[16], acc1[16];
#pragma unroll
    for (int c = 0; c < 16; ++c) { acc0[c] = 0.f; acc1[c] = 0.f; }

    for (int kb = 0; kb < 128; kb += 32) {
        // stage W chunk: rows kb..kb+31, all 128 cols
        {
            int kk = tid >> 3;
            int cc = (tid & 7) * 16;
            const float4* wp = (const float4*)(W + (size_t)(kb + kk) * 128 + cc);
            float4 w0 = wp[0], w1 = wp[1], w2 = wp[2], w3 = wp[3];
            float* dw = &Wt[kk][cc];
            dw[0] = w0.x; dw[1] = w0.y; dw[2] = w0.z; dw[3] = w0.w;
            dw[4] = w1.x; dw[5] = w1.y; dw[6] = w1.z; dw[7] = w1.w;
            dw[8] = w2.x; dw[9] = w2.y; dw[10] = w2.z; dw[11] = w2.w;
            dw[12] = w3.x; dw[13] = w3.y; dw[14] = w3.z; dw[15] = w3.w;
        }
        // stage X chunk (64 rows x 32 k)
        {
            int rr = tid >> 2;
            int kx = (tid & 3) * 8;
            int gr = r0 + rr;
            float vals[8];
            if (gr < n) {
                if (mode == 0) {
                    const float4* xp = (const float4*)(feat + (size_t)gr * 128 + kb + kx);
                    float4 a = xp[0], bq = xp[1];
                    vals[0] = a.x; vals[1] = a.y; vals[2] = a.z; vals[3] = a.w;
                    vals[4] = bq.x; vals[5] = bq.y; vals[6] = bq.z; vals[7] = bq.w;
                } else {
                    int orow = oldid[gr];
                    float g = garr[gr];
                    const float4* xp = (const float4*)(xprev + (size_t)orow * 128 + kb + kx);
                    float4 a = xp[0], bq = xp[1];
                    vals[0] = a.x * g; vals[1] = a.y * g; vals[2] = a.z * g; vals[3] = a.w * g;
                    vals[4] = bq.x * g; vals[5] = bq.y * g; vals[6] = bq.z * g; vals[7] = bq.w * g;
                }
            } else {
#pragma unroll
                for (int q2 = 0; q2 < 8; ++q2) vals[q2] = 0.f;
            }
            float* dx = &Xt[rr][kx];
#pragma unroll
            for (int q2 = 0; q2 < 8; ++q2) dx[q2] = vals[q2];
        }
        __syncthreads();
#pragma unroll 4
        for (int kk = 0; kk < 32; ++kk) {
            float x0 = Xt[rl0][kk], x1 = Xt[rl0 + 1][kk];
#pragma unroll
            for (int c = 0; c < 16; ++c) {
                float wv = Wt[kk][c0 + c];
                acc0[c] = fmaf(x0, wv, acc0[c]);
                acc1[c] = fmaf(x1, wv, acc1[c]);
            }
        }
        __syncthreads();
    }
    int gr0 = r0 + rl0;
    if (gr0 < n) {
        float* op = hpre + (size_t)gr0 * 128 + c0;
#pragma unroll
        for (int c = 0; c < 16; ++c) op[c] = acc0[c];
    }
    int gr1 = gr0 + 1;
    if (gr1 < n) {
        float* op = hpre + (size_t)gr1 * 128 + c0;
#pragma unroll
        for (int c = 0; c < 16; ++c) op[c] = acc1[c];
    }
}

// one wave per node: h_post[d] = relu(nd[d]*sum_in h_pre[src]*ns[src] + cb); hs[d] = h_post[d].sW
__global__ __launch_bounds__(256) void k_agg_conv(
        const float* __restrict__ hpre, const int* __restrict__ ptr,
        const int* __restrict__ csr_src, const float* __restrict__ nsv,
        const float* __restrict__ ndv, const float* __restrict__ cb,
        const float* __restrict__ sW, float* __restrict__ hpost,
        float* __restrict__ hs, int n) {
    int wid = threadIdx.x >> 6;
    int lane = threadIdx.x & 63;
    int d = blockIdx.x * 4 + wid;
    if (d >= n) return;
    int p0 = ptr[d], p1 = ptr[d + 1];
    float a0 = 0.f, a1 = 0.f;
    for (int s2 = p0; s2 < p1; ++s2) {
        int s = csr_src[s2];
        float w = nsv[s];
        float2 hv = ((const float2*)(hpre + (size_t)s * 128))[lane];
        a0 = fmaf(hv.x, w, a0);
        a1 = fmaf(hv.y, w, a1);
    }
    float nd2 = ndv[d];
    int c0 = lane * 2;
    float h0 = fmaxf(fmaf(a0, nd2, cb[c0]), 0.f);
    float h1 = fmaxf(fmaf(a1, nd2, cb[c0 + 1]), 0.f);
    ((float2*)(hpost + (size_t)d * 128))[lane] = make_float2(h0, h1);
    float v = h0 * sW[c0] + h1 * sW[c0 + 1];
#pragma unroll
    for (int off = 32; off; off >>= 1) v += __shfl_down(v, off);
    if (lane == 0) hs[d] = v;
}

__global__ void k_agg_score(const float* __restrict__ hs, const int* __restrict__ ptr,
                            const int* __restrict__ csr_src, const float* __restrict__ nsv,
                            const float* __restrict__ ndv, const float* __restrict__ sb,
                            float* score, int n) {
    int d = blockIdx.x * blockDim.x + threadIdx.x;
    if (d >= n) return;
    int p0 = ptr[d], p1 = ptr[d + 1];
    float sum = 0.f;
    for (int s2 = p0; s2 < p1; ++s2) {
        int s = csr_src[s2];
        sum = fmaf(hs[s], nsv[s], sum);
    }
    score[d] = ndv[d] * sum + sb[0];
}

// single-block radix select: ctrl[0]=threshold key T, ctrl[1]=count(key>T), ctrl[2]=k-G
__global__ void k_radix(const float* __restrict__ score, int n, int k, int* ctrl) {
    __shared__ int hist[256];
    __shared__ unsigned sprefix;
    __shared__ int skneed, sG;
    int tid = threadIdx.x;
    if (tid == 0) { sprefix = 0u; skneed = k; sG = 0; }
    __syncthreads();
    for (int pass = 0; pass < 4; ++pass) {
        const unsigned hmtab[4] = {0x00000000u, 0xFF000000u, 0xFFFF0000u, 0xFFFFFF00u};
        int shift = 24 - 8 * pass;
        unsigned himask = hmtab[pass];
        if (tid < 256) hist[tid] = 0;
        __syncthreads();
        unsigned pfx = sprefix;
        for (int i = tid; i < n; i += 1024) {
            unsigned u = fkey(score[i]);
            if ((u & himask) == pfx) atomicAdd(&hist[(u >> shift) & 255], 1);
        }
        __syncthreads();
        if (tid == 0) {
            int kneed = skneed, cum = 0, d = 255;
            for (; d >= 1; --d) {
                int c = hist[d];
                if (cum + c >= kneed) break;
                cum += c;
            }
            sG += cum;
            skneed = kneed - cum;
            sprefix = pfx | ((unsigned)d << shift);
        }
        __syncthreads();
    }
    if (tid == 0) { ctrl[0] = (int)sprefix; ctrl[1] = sG; ctrl[2] = k - sG; }
}

// sequential-chunk compaction: selected = key>T, plus first (k-G) lowest-index keys==T.
__global__ void k_compact(const float* __restrict__ score, const int* __restrict__ ctrl, int n,
                          int* newid, int* oldid, float* garr, float* maxbuf) {
    __shared__ int wsumE[16], wsumS[16];
    __shared__ int sEqBefore, sSelBefore, sEqTot, sSelTot;
    unsigned T = (unsigned)ctrl[0];
    int needEq = ctrl[2];
    int tid = threadIdx.x, lane = tid & 63, wid = tid >> 6;
    if (tid == 0) { sEqBefore = 0; sSelBefore = 0; }
    if (tid < 128) maxbuf[tid] = NEG_HUGE;
    __syncthreads();
    for (int base = 0; base < n; base += 1024) {
        int i = base + tid;
        float sc = (i < n) ? score[i] : 0.f;
        unsigned u = fkey(sc);
        bool inb = (i < n);
        bool isG = inb && (u > T);
        bool isE = inb && (u == T);
        int eInc = waveInclScan(isE ? 1 : 0, lane);
        if (lane == 63) wsumE[wid] = eInc;
        __syncthreads();
        if (tid == 0) {
            int run = 0;
            for (int w = 0; w < 16; ++w) { int t2 = wsumE[w]; wsumE[w] = run; run += t2; }
            sEqTot = run;
        }
        __syncthreads();
        int eqRank = sEqBefore + wsumE[wid] + eInc - (isE ? 1 : 0);
        bool sel = isG || (isE && (eqRank < needEq));
        int sInc = waveInclScan(sel ? 1 : 0, lane);
        if (lane == 63) wsumS[wid] = sInc;
        __syncthreads();
        if (tid == 0) {
            int run = 0;
            for (int w = 0; w < 16; ++w) { int t2 = wsumS[w]; wsumS[w] = run; run += t2; }
            sSelTot = run;
        }
        __syncthreads();
        if (inb) {
            if (sel) {
                int j = sSelBefore + wsumS[wid] + sInc - 1;
                newid[i] = j;
                oldid[j] = i;
                garr[j] = tanhf(sc);
            } else {
                newid[i] = -1;
            }
        }
        __syncthreads();
        if (tid == 0) { sEqBefore += sEqTot; sSelBefore += sSelTot; }
        __syncthreads();
    }
}

// hardening: clamp any invalid oldid (keeps failures finite & diagnosable)
__global__ void k_fixup(int* oldid, float* garr, int k, int n) {
    int j = blockIdx.x * blockDim.x + threadIdx.x;
    if (j >= k) return;
    int o = oldid[j];
    if (o < 0 || o >= n) { oldid[j] = 0; garr[j] = 0.f; }
}

__global__ void k_remap(const int* __restrict__ newid, int* cur_src, int* cur_dst) {
    int e = blockIdx.x * blockDim.x + threadIdx.x;
    if (e >= NEDGE) return;
    int s = cur_src[e];
    if (s < 0) return;
    int d = cur_dst[e];
    int ns2 = newid[s], nd2 = newid[d];
    if (ns2 >= 0 && nd2 >= 0) { cur_src[e] = ns2; cur_dst[e] = nd2; }
    else cur_src[e] = -1;
}

__global__ void k_readout(const float* __restrict__ hpost, const int* __restrict__ oldid,
                          const float* __restrict__ garr, float* finalv, float* maxbuf,
                          int k, float invk) {
    int c = threadIdx.x;  // 128
    float sum = 0.f, mx = NEG_HUGE;
    for (int r = blockIdx.x; r < k; r += gridDim.x) {
        float g = garr[r];
        const float* row = hpost + (size_t)oldid[r] * 128;
        float v = row[c] * g;
        sum += v;
        mx = fmaxf(mx, v);
    }
    atomicAdd(&finalv[c], sum * invk);
    atomicMaxF(&maxbuf[c], mx);
}

__global__ void k_finish(float* finalv, const float* __restrict__ maxbuf) {
    int c = threadIdx.x;  // 128
    finalv[128 + c] += maxbuf[c];
}

__global__ void k_mlp1(const float* __restrict__ finalv, const float* __restrict__ seq,
                       const float* __restrict__ W1, float* f1raw) {
    int o = threadIdx.x;             // 256
    int j0 = blockIdx.x * 128;       // 10 blocks
    float acc = 0.f;
    for (int jj = 0; jj < 128; ++jj) {
        int j = j0 + jj;
        float fv = (j < 256) ? finalv[j] : seq[j - 256];
        acc = fmaf(fv, W1[(size_t)j * 256 + o], acc);
    }
    atomicAdd(&f1raw[o], acc);
}

__global__ void k_mlp2(const float* __restrict__ f1raw, const float* __restrict__ b1,
                       const float* __restrict__ W2, const float* __restrict__ bb2,
                       float* f2v) {
    __shared__ float f1s[256];
    int t = threadIdx.x;  // 128
    f1s[t] = fmaxf(f1raw[t] + b1[t], 0.f);
    f1s[t + 128] = fmaxf(f1raw[t + 128] + b1[t + 128], 0.f);
    __syncthreads();
    float acc = 0.f;
    for (int j = 0; j < 256; ++j)
        acc = fmaf(f1s[j], W2[(size_t)j * 128 + t], acc);
    f2v[t] = fmaxf(acc + bb2[t], 0.f);
}

__global__ void k_mlp3(const float* __restrict__ f2v, const float* __restrict__ W3,
                       const float* __restrict__ b3, float* out) {
    __shared__ float f2s[128];
    int t = threadIdx.x;  // 128
    f2s[t] = f2v[t];
    __syncthreads();
    int col = blockIdx.x * 128 + t;  // 16 blocks
    float acc = 0.f;
    for (int j = 0; j < 128; ++j)
        acc = fmaf(f2s[j], W3[(size_t)j * 2048 + col], acc);
    out[col] = acc + b3[col];
}

// ---------- host ----------
extern "C" void kernel_launch(void* const* d_in, const int* in_sizes, int n_in,
                              void* d_out, int out_size, void* d_ws, size_t ws_size,
                              hipStream_t stream) {
    (void)in_sizes; (void)n_in; (void)out_size; (void)ws_size;
    const float* feat = (const float*)d_in[0];
    const float* seq  = (const float*)d_in[1];
    const int* src = (const int*)d_in[2];
    const int* dst = (const int*)d_in[3];
    // d_in[4], d_in[5]: label_src/label_dst — dead code in reference, unused.
    const float *cW[3], *cb[3], *sW[3], *sb[3];
    for (int b = 0; b < 3; ++b) {
        cW[b] = (const float*)d_in[6 + 4 * b];
        cb[b] = (const float*)d_in[7 + 4 * b];
        sW[b] = (const float*)d_in[8 + 4 * b];
        sb[b] = (const float*)d_in[9 + 4 * b];
    }
    const float* lin1W = (const float*)d_in[18];
    const float* lin1b = (const float*)d_in[19];
    const float* lin2W = (const float*)d_in[20];
    const float* lin2b = (const float*)d_in[21];
    const float* lin3W = (const float*)d_in[22];
    const float* lin3b = (const float*)d_in[23];
    float* out = (float*)d_out;

    char* p = (char*)d_ws;
    size_t off = 0;
    auto alloc = [&](size_t bytes) -> void* {
        void* r = p + off;
        off = (off + bytes + 255) & ~(size_t)255;
        return r;
    };
    float* buf0   = (float*)alloc((size_t)N0 * 128 * 4);   // h_pre
    float* buf1   = (float*)alloc((size_t)N0 * 128 * 4);   // h_post
    float* hs     = (float*)alloc((size_t)N0 * 4);
    float* score  = (float*)alloc((size_t)N0 * 4);
    float* nsv    = (float*)alloc((size_t)N0 * 4);
    float* ndv    = (float*)alloc((size_t)N0 * 4);
    int* deg_in   = (int*)alloc((size_t)N0 * 4);
    int* deg_out  = (int*)alloc((size_t)N0 * 4);
    int* cur_src  = (int*)alloc((size_t)NEDGE * 4);
    int* cur_dst  = (int*)alloc((size_t)NEDGE * 4);
    int* csr_src  = (int*)alloc((size_t)NEDGE * 4);
    int* csr_ptr  = (int*)alloc((size_t)(N0 + 1) * 4);
    int* fill     = (int*)alloc((size_t)N0 * 4);
    int* newid    = (int*)alloc((size_t)N0 * 4);
    int* oldid    = (int*)alloc((size_t)25000 * 4);
    float* garr   = (float*)alloc((size_t)25000 * 4);
    float* maxbuf = (float*)alloc(128 * 4);
    float* finalv = (float*)alloc(256 * 4);
    float* f1raw  = (float*)alloc(256 * 4);
    float* f2v    = (float*)alloc(128 * 4);
    int* ctrl     = (int*)alloc(64 * 4);

    const int nb[3] = {50000, 25000, 12500};
    const int kb[3] = {25000, 12500, 6250};

    k_init<<<(NEDGE + 255) / 256, 256, 0, stream>>>(src, dst, cur_src, cur_dst, finalv, f1raw);

    for (int b = 0; b < 3; ++b) {
        int n = nb[b], k = kb[b];
        k_zero<<<(n + 255) / 256, 256, 0, stream>>>(deg_in, deg_out, fill, n);
        k_hist<<<(NEDGE + 255) / 256, 256, 0, stream>>>(cur_src, cur_dst, deg_in, deg_out);
        k_norms<<<(n + 255) / 256, 256, 0, stream>>>(deg_in, deg_out, nsv, ndv, n);
        k_scan<<<1, 1024, 0, stream>>>(deg_in, csr_ptr, n);
        k_fill<<<(NEDGE + 255) / 256, 256, 0, stream>>>(cur_src, cur_dst, csr_ptr, fill, csr_src);
        k_gemm<<<(n + 63) / 64, 256, 0, stream>>>(feat, buf1, oldid, garr, cW[b], buf0, n,
                                                  (b == 0) ? 0 : 1);
        k_agg_conv<<<(n + 3) / 4, 256, 0, stream>>>(buf0, csr_ptr, csr_src, nsv, ndv, cb[b],
                                                    sW[b], buf1, hs, n);
        k_agg_score<<<(n + 255) / 256, 256, 0, stream>>>(hs, csr_ptr, csr_src, nsv, ndv, sb[b],
                                                         score, n);
        k_radix<<<1, 1024, 0, stream>>>(score, n, k, ctrl);
        k_compact<<<1, 1024, 0, stream>>>(score, ctrl, n, newid, oldid, garr, maxbuf);
        k_fixup<<<(k + 255) / 256, 256, 0, stream>>>(oldid, garr, k, n);
        k_readout<<<256, 128, 0, stream>>>(buf1, oldid, garr, finalv, maxbuf, k, 1.0f / (float)k);
        k_finish<<<1, 128, 0, stream>>>(finalv, maxbuf);
        if (b < 2) k_remap<<<(NEDGE + 255) / 256, 256, 0, stream>>>(newid, cur_src, cur_dst);
    }

    k_mlp1<<<10, 256, 0, stream>>>(finalv, seq, lin1W, f1raw);
    k_mlp2<<<1, 128, 0, stream>>>(f1raw, lin1b, lin2W, lin2b, f2v);
    k_mlp3<<<16, 128, 0, stream>>>(f2v, lin3W, lin3b, out);
}

// Round 4
// 860.723 us; speedup vs baseline: 1.2419x; 1.2419x over previous
//
#include <hip/hip_runtime.h>
#include <hip/hip_bf16.h>
#include <cmath>

#define N0 50000
#define NEDGE 800000
#define NEG_HUGE -3.402823466e38f
#define BMAX 64

// ---------- helpers ----------
__device__ inline unsigned fkey(float f) {
    unsigned b = __float_as_uint(f);
    if (b == 0x80000000u) b = 0u;  // canonicalize -0 -> +0
    return (b & 0x80000000u) ? ~b : (b | 0x80000000u);
}

__device__ inline void atomicMaxF(float* a, float v) {
    if (v >= 0.f) atomicMax((int*)a, __float_as_int(v));
    else          atomicMin((unsigned int*)a, __float_as_uint(v));
}

__device__ inline int waveInclScan(int v, int lane) {
#pragma unroll
    for (int off = 1; off < 64; off <<= 1) {
        int t = __shfl_up(v, off);
        if (lane >= off) v += t;
    }
    return v;
}

// ---------- graph prep ----------
__global__ void k_init(const int* __restrict__ src, const int* __restrict__ dst,
                       int* cur_src, int* cur_dst, float* finalv, float* f1raw) {
    int i = blockIdx.x * blockDim.x + threadIdx.x;
    if (i < NEDGE) { cur_src[i] = src[i]; cur_dst[i] = dst[i]; }
    if (i < 256) { finalv[i] = 0.f; f1raw[i] = 0.f; }
}

__global__ void k_zero(int* deg_in, int* deg_out, int* fill, int n) {
    int i = blockIdx.x * blockDim.x + threadIdx.x;
    if (i < n) { deg_in[i] = 0; deg_out[i] = 0; fill[i] = 0; }
}

__global__ void k_hist(const int* __restrict__ cs, const int* __restrict__ cd,
                       int* deg_in, int* deg_out) {
    int e = blockIdx.x * blockDim.x + threadIdx.x;
    if (e >= NEDGE) return;
    int s = cs[e];
    if (s < 0) return;
    atomicAdd(&deg_out[s], 1);
    atomicAdd(&deg_in[cd[e]], 1);
}

__global__ void k_norms(const int* __restrict__ deg_in, const int* __restrict__ deg_out,
                        float* nsv, float* ndv, int n) {
    int i = blockIdx.x * blockDim.x + threadIdx.x;
    if (i >= n) return;
    nsv[i] = rsqrtf(fmaxf((float)deg_out[i], 1.f));
    ndv[i] = rsqrtf(fmaxf((float)deg_in[i], 1.f));
}

// ---------- parallel CSR-ptr scan (3 kernels) ----------
__global__ void k_pcnt(const int* __restrict__ deg, int* pcnt, int n) {
    __shared__ int wsum[16];
    int b = blockIdx.x;
    int i = b * 1024 + threadIdx.x;
    int lane = threadIdx.x & 63, wid = threadIdx.x >> 6;
    int v = (i < n) ? deg[i] : 0;
#pragma unroll
    for (int off = 32; off; off >>= 1) v += __shfl_down(v, off);
    if (lane == 0) wsum[wid] = v;
    __syncthreads();
    if (threadIdx.x == 0) {
        int s = 0;
#pragma unroll
        for (int w = 0; w < 16; ++w) s += wsum[w];
        pcnt[b] = s;
    }
}

__global__ void k_pscan(const int* __restrict__ pcnt, int* poff, int* ptr, int n, int B) {
    if (threadIdx.x == 0) {
        int run = 0;
        for (int b = 0; b < B; ++b) { poff[b] = run; run += pcnt[b]; }
        ptr[n] = run;
    }
}

__global__ void k_pemit(const int* __restrict__ deg, const int* __restrict__ poff,
                        int* ptr, int n) {
    __shared__ int wsum[16];
    int b = blockIdx.x;
    int i = b * 1024 + threadIdx.x;
    int lane = threadIdx.x & 63, wid = threadIdx.x >> 6;
    int v = (i < n) ? deg[i] : 0;
    int inc = waveInclScan(v, lane);
    if (lane == 63) wsum[wid] = inc;
    __syncthreads();
    int woff = 0;
    for (int w = 0; w < wid; ++w) woff += wsum[w];
    if (i < n) ptr[i] = poff[b] + woff + inc - v;
}

__global__ void k_fill(const int* __restrict__ cs, const int* __restrict__ cd,
                       const int* __restrict__ ptr, int* fill, int* csr_src) {
    int e = blockIdx.x * blockDim.x + threadIdx.x;
    if (e >= NEDGE) return;
    int s = cs[e];
    if (s < 0) return;
    int d = cd[e];
    int pos = atomicAdd(&fill[d], 1);
    csr_src[ptr[d] + pos] = s;
}

// ---------- GEMM: h_pre = X @ W ----------
__global__ __launch_bounds__(256) void k_gemm(
        const float* __restrict__ feat, const float* __restrict__ xprev,
        const int* __restrict__ oldid, const float* __restrict__ garr,
        const float* __restrict__ W, float* __restrict__ hpre, int n, int mode) {
    __shared__ float Wt[32][132];
    __shared__ float Xt[64][33];
    int tid = threadIdx.x;
    int r0 = blockIdx.x * 64;
    int c0 = (tid & 7) * 16;
    int rl0 = (tid >> 3) * 2;
    float acc0[16], acc1[16];
#pragma unroll
    for (int c = 0; c < 16; ++c) { acc0[c] = 0.f; acc1[c] = 0.f; }

    for (int kb = 0; kb < 128; kb += 32) {
        {
            int kk = tid >> 3;
            int cc = (tid & 7) * 16;
            const float4* wp = (const float4*)(W + (size_t)(kb + kk) * 128 + cc);
            float4 w0 = wp[0], w1 = wp[1], w2 = wp[2], w3 = wp[3];
            float* dw = &Wt[kk][cc];
            dw[0] = w0.x; dw[1] = w0.y; dw[2] = w0.z; dw[3] = w0.w;
            dw[4] = w1.x; dw[5] = w1.y; dw[6] = w1.z; dw[7] = w1.w;
            dw[8] = w2.x; dw[9] = w2.y; dw[10] = w2.z; dw[11] = w2.w;
            dw[12] = w3.x; dw[13] = w3.y; dw[14] = w3.z; dw[15] = w3.w;
        }
        {
            int rr = tid >> 2;
            int kx = (tid & 3) * 8;
            int gr = r0 + rr;
            float vals[8];
            if (gr < n) {
                if (mode == 0) {
                    const float4* xp = (const float4*)(feat + (size_t)gr * 128 + kb + kx);
                    float4 a = xp[0], bq = xp[1];
                    vals[0] = a.x; vals[1] = a.y; vals[2] = a.z; vals[3] = a.w;
                    vals[4] = bq.x; vals[5] = bq.y; vals[6] = bq.z; vals[7] = bq.w;
                } else {
                    int orow = oldid[gr];
                    float g = garr[gr];
                    const float4* xp = (const float4*)(xprev + (size_t)orow * 128 + kb + kx);
                    float4 a = xp[0], bq = xp[1];
                    vals[0] = a.x * g; vals[1] = a.y * g; vals[2] = a.z * g; vals[3] = a.w * g;
                    vals[4] = bq.x * g; vals[5] = bq.y * g; vals[6] = bq.z * g; vals[7] = bq.w * g;
                }
            } else {
#pragma unroll
                for (int q2 = 0; q2 < 8; ++q2) vals[q2] = 0.f;
            }
            float* dx = &Xt[rr][kx];
#pragma unroll
            for (int q2 = 0; q2 < 8; ++q2) dx[q2] = vals[q2];
        }
        __syncthreads();
#pragma unroll 4
        for (int kk = 0; kk < 32; ++kk) {
            float x0 = Xt[rl0][kk], x1 = Xt[rl0 + 1][kk];
#pragma unroll
            for (int c = 0; c < 16; ++c) {
                float wv = Wt[kk][c0 + c];
                acc0[c] = fmaf(x0, wv, acc0[c]);
                acc1[c] = fmaf(x1, wv, acc1[c]);
            }
        }
        __syncthreads();
    }
    int gr0 = r0 + rl0;
    if (gr0 < n) {
        float* op = hpre + (size_t)gr0 * 128 + c0;
#pragma unroll
        for (int c = 0; c < 16; ++c) op[c] = acc0[c];
    }
    int gr1 = gr0 + 1;
    if (gr1 < n) {
        float* op = hpre + (size_t)gr1 * 128 + c0;
#pragma unroll
        for (int c = 0; c < 16; ++c) op[c] = acc1[c];
    }
}

// ---------- edge aggregation ----------
__global__ __launch_bounds__(256) void k_agg_conv(
        const float* __restrict__ hpre, const int* __restrict__ ptr,
        const int* __restrict__ csr_src, const float* __restrict__ nsv,
        const float* __restrict__ ndv, const float* __restrict__ cb,
        const float* __restrict__ sW, float* __restrict__ hpost,
        float* __restrict__ hs, int n) {
    int wid = threadIdx.x >> 6;
    int lane = threadIdx.x & 63;
    int d = blockIdx.x * 4 + wid;
    if (d >= n) return;
    int p0 = ptr[d], p1 = ptr[d + 1];
    float a0 = 0.f, a1 = 0.f;
    for (int s2 = p0; s2 < p1; ++s2) {
        int s = csr_src[s2];
        float w = nsv[s];
        float2 hv = ((const float2*)(hpre + (size_t)s * 128))[lane];
        a0 = fmaf(hv.x, w, a0);
        a1 = fmaf(hv.y, w, a1);
    }
    float nd2 = ndv[d];
    int c0 = lane * 2;
    float h0 = fmaxf(fmaf(a0, nd2, cb[c0]), 0.f);
    float h1 = fmaxf(fmaf(a1, nd2, cb[c0 + 1]), 0.f);
    ((float2*)(hpost + (size_t)d * 128))[lane] = make_float2(h0, h1);
    float v = h0 * sW[c0] + h1 * sW[c0 + 1];
#pragma unroll
    for (int off = 32; off; off >>= 1) v += __shfl_down(v, off);
    if (lane == 0) hs[d] = v;
}

__global__ void k_agg_score(const float* __restrict__ hs, const int* __restrict__ ptr,
                            const int* __restrict__ csr_src, const float* __restrict__ nsv,
                            const float* __restrict__ ndv, const float* __restrict__ sb,
                            float* score, int n) {
    int d = blockIdx.x * blockDim.x + threadIdx.x;
    if (d >= n) return;
    int p0 = ptr[d], p1 = ptr[d + 1];
    float sum = 0.f;
    for (int s2 = p0; s2 < p1; ++s2) {
        int s = csr_src[s2];
        sum = fmaf(hs[s], nsv[s], sum);
    }
    score[d] = ndv[d] * sum + sb[0];
}

// ---------- parallel radix top-k select ----------
// ctrl[0]=prefix/T, ctrl[1]=kneed, ctrl[2]=needEq (final)
__global__ void k_rzero(int* gbins, int* ctrl) {
    gbins[threadIdx.x] = 0;
    if (threadIdx.x == 0) ctrl[0] = 0;
}

__global__ void k_rhist(const float* __restrict__ score, const int* __restrict__ ctrl,
                        int n, int pass, int* gbins) {
    __shared__ int h[256];
    int tid = threadIdx.x;
    h[tid] = 0;
    __syncthreads();
    const unsigned hmtab[4] = {0x00000000u, 0xFF000000u, 0xFFFF0000u, 0xFFFFFF00u};
    unsigned himask = hmtab[pass];
    unsigned prefix = (unsigned)ctrl[0];
    int shift = 24 - 8 * pass;
    for (int i = blockIdx.x * 256 + tid; i < n; i += gridDim.x * 256) {
        unsigned u = fkey(score[i]);
        if ((u & himask) == prefix) atomicAdd(&h[(u >> shift) & 255], 1);
    }
    __syncthreads();
    if (h[tid]) atomicAdd(&gbins[tid], h[tid]);
}

__global__ void k_rpick(int pass, int k0, int* ctrl, int* gbins) {
    __shared__ int h[256];
    int tid = threadIdx.x;
    h[tid] = gbins[tid];
    gbins[tid] = 0;  // ready for next pass
    __syncthreads();
    if (tid == 0) {
        int shift = 24 - 8 * pass;
        int kneed = (pass == 0) ? k0 : ctrl[1];
        int cum = 0, d = 255;
        for (; d >= 1; --d) {
            int c = h[d];
            if (cum + c >= kneed) break;
            cum += c;
        }
        ctrl[0] = (int)(((unsigned)ctrl[0]) | ((unsigned)d << shift));
        ctrl[1] = kneed - cum;
        if (pass == 3) ctrl[2] = kneed - cum;  // needEq
    }
}

// ---------- parallel compaction (3 kernels) ----------
__global__ void k_ccnt(const float* __restrict__ score, const int* __restrict__ ctrl,
                       int n, int* cntG, int* cntE) {
    __shared__ int wG[16], wE[16];
    int b = blockIdx.x;
    int i = b * 1024 + threadIdx.x;
    int lane = threadIdx.x & 63, wid = threadIdx.x >> 6;
    unsigned T = (unsigned)ctrl[0];
    bool inb = (i < n);
    unsigned u = inb ? fkey(score[i]) : 0u;
    bool isG = inb && (u > T);
    bool isE = inb && (u == T);
    unsigned long long mG = __ballot(isG);
    unsigned long long mE = __ballot(isE);
    if (lane == 0) { wG[wid] = __popcll(mG); wE[wid] = __popcll(mE); }
    __syncthreads();
    if (threadIdx.x == 0) {
        int sg = 0, se = 0;
#pragma unroll
        for (int w = 0; w < 16; ++w) { sg += wG[w]; se += wE[w]; }
        cntG[b] = sg; cntE[b] = se;
    }
}

__global__ void k_cscan(const int* __restrict__ cntG, const int* __restrict__ cntE,
                        int* coffG, int* coffE, int B, float* maxbuf) {
    int tid = threadIdx.x;  // 256
    if (tid < 128) maxbuf[tid] = NEG_HUGE;
    if (tid == 0) {
        int rg = 0, re = 0;
        for (int b = 0; b < B; ++b) {
            coffG[b] = rg; coffE[b] = re;
            rg += cntG[b]; re += cntE[b];
        }
    }
}

__global__ void k_cemit(const float* __restrict__ score, const int* __restrict__ ctrl,
                        const int* __restrict__ coffG, const int* __restrict__ coffE,
                        int n, int* newid, int* oldid, float* garr) {
    __shared__ int wG[16], wE[16];
    int b = blockIdx.x;
    int i = b * 1024 + threadIdx.x;
    int lane = threadIdx.x & 63, wid = threadIdx.x >> 6;
    unsigned T = (unsigned)ctrl[0];
    int needEq = ctrl[2];
    bool inb = (i < n);
    float sc = inb ? score[i] : 0.f;
    unsigned u = inb ? fkey(sc) : 0u;
    bool isG = inb && (u > T);
    bool isE = inb && (u == T);
    unsigned long long mG = __ballot(isG);
    unsigned long long mE = __ballot(isE);
    if (lane == 0) { wG[wid] = __popcll(mG); wE[wid] = __popcll(mE); }
    __syncthreads();
    unsigned long long below = (1ull << lane) - 1ull;
    int gW = 0, eW = 0;
    for (int w = 0; w < wid; ++w) { gW += wG[w]; eW += wE[w]; }
    int Gb = coffG[b] + gW + __popcll(mG & below);
    int Eb = coffE[b] + eW + __popcll(mE & below);
    if (inb) {
        bool sel = isG || (isE && (Eb < needEq));
        if (sel) {
            int j = Gb + min(Eb, needEq);
            newid[i] = j;
            oldid[j] = i;
            garr[j] = tanhf(sc);
        } else {
            newid[i] = -1;
        }
    }
}

// hardening: clamp any invalid oldid (keeps failures finite & diagnosable)
__global__ void k_fixup(int* oldid, float* garr, int k, int n) {
    int j = blockIdx.x * blockDim.x + threadIdx.x;
    if (j >= k) return;
    int o = oldid[j];
    if (o < 0 || o >= n) { oldid[j] = 0; garr[j] = 0.f; }
}

__global__ void k_remap(const int* __restrict__ newid, int* cur_src, int* cur_dst) {
    int e = blockIdx.x * blockDim.x + threadIdx.x;
    if (e >= NEDGE) return;
    int s = cur_src[e];
    if (s < 0) return;
    int d = cur_dst[e];
    int ns2 = newid[s], nd2 = newid[d];
    if (ns2 >= 0 && nd2 >= 0) { cur_src[e] = ns2; cur_dst[e] = nd2; }
    else cur_src[e] = -1;
}

__global__ void k_readout(const float* __restrict__ hpost, const int* __restrict__ oldid,
                          const float* __restrict__ garr, float* finalv, float* maxbuf,
                          int k, float invk) {
    int c = threadIdx.x;  // 128
    float sum = 0.f, mx = NEG_HUGE;
    for (int r = blockIdx.x; r < k; r += gridDim.x) {
        float g = garr[r];
        const float* row = hpost + (size_t)oldid[r] * 128;
        float v = row[c] * g;
        sum += v;
        mx = fmaxf(mx, v);
    }
    atomicAdd(&finalv[c], sum * invk);
    atomicMaxF(&maxbuf[c], mx);
}

__global__ void k_finish(float* finalv, const float* __restrict__ maxbuf) {
    int c = threadIdx.x;  // 128
    finalv[128 + c] += maxbuf[c];
}

// ---------- final MLP ----------
__global__ void k_mlp1(const float* __restrict__ finalv, const float* __restrict__ seq,
                       const float* __restrict__ W1, float* f1raw) {
    int o = threadIdx.x;             // 256
    int j0 = blockIdx.x * 128;       // 10 blocks
    float acc = 0.f;
    for (int jj = 0; jj < 128; ++jj) {
        int j = j0 + jj;
        float fv = (j < 256) ? finalv[j] : seq[j - 256];
        acc = fmaf(fv, W1[(size_t)j * 256 + o], acc);
    }
    atomicAdd(&f1raw[o], acc);
}

__global__ void k_mlp2(const float* __restrict__ f1raw, const float* __restrict__ b1,
                       const float* __restrict__ W2, const float* __restrict__ bb2,
                       float* f2v) {
    __shared__ float f1s[256];
    int t = threadIdx.x;  // 128
    f1s[t] = fmaxf(f1raw[t] + b1[t], 0.f);
    f1s[t + 128] = fmaxf(f1raw[t + 128] + b1[t + 128], 0.f);
    __syncthreads();
    float acc = 0.f;
    for (int j = 0; j < 256; ++j)
        acc = fmaf(f1s[j], W2[(size_t)j * 128 + t], acc);
    f2v[t] = fmaxf(acc + bb2[t], 0.f);
}

__global__ void k_mlp3(const float* __restrict__ f2v, const float* __restrict__ W3,
                       const float* __restrict__ b3, float* out) {
    __shared__ float f2s[128];
    int t = threadIdx.x;  // 128
    f2s[t] = f2v[t];
    __syncthreads();
    int col = blockIdx.x * 128 + t;  // 16 blocks
    float acc = 0.f;
    for (int j = 0; j < 128; ++j)
        acc = fmaf(f2s[j], W3[(size_t)j * 2048 + col], acc);
    out[col] = acc + b3[col];
}

// ---------- host ----------
extern "C" void kernel_launch(void* const* d_in, const int* in_sizes, int n_in,
                              void* d_out, int out_size, void* d_ws, size_t ws_size,
                              hipStream_t stream) {
    (void)in_sizes; (void)n_in; (void)out_size; (void)ws_size;
    const float* feat = (const float*)d_in[0];
    const float* seq  = (const float*)d_in[1];
    const int* src = (const int*)d_in[2];
    const int* dst = (const int*)d_in[3];
    // d_in[4], d_in[5]: label_src/label_dst — dead code in reference, unused.
    const float *cW[3], *cb[3], *sW[3], *sb[3];
    for (int b = 0; b < 3; ++b) {
        cW[b] = (const float*)d_in[6 + 4 * b];
        cb[b] = (const float*)d_in[7 + 4 * b];
        sW[b] = (const float*)d_in[8 + 4 * b];
        sb[b] = (const float*)d_in[9 + 4 * b];
    }
    const float* lin1W = (const float*)d_in[18];
    const float* lin1b = (const float*)d_in[19];
    const float* lin2W = (const float*)d_in[20];
    const float* lin2b = (const float*)d_in[21];
    const float* lin3W = (const float*)d_in[22];
    const float* lin3b = (const float*)d_in[23];
    float* out = (float*)d_out;

    char* p = (char*)d_ws;
    size_t off = 0;
    auto alloc = [&](size_t bytes) -> void* {
        void* r = p + off;
        off = (off + bytes + 255) & ~(size_t)255;
        return r;
    };
    float* buf0   = (float*)alloc((size_t)N0 * 128 * 4);   // h_pre
    float* buf1   = (float*)alloc((size_t)N0 * 128 * 4);   // h_post
    float* hs     = (float*)alloc((size_t)N0 * 4);
    float* score  = (float*)alloc((size_t)N0 * 4);
    float* nsv    = (float*)alloc((size_t)N0 * 4);
    float* ndv    = (float*)alloc((size_t)N0 * 4);
    int* deg_in   = (int*)alloc((size_t)N0 * 4);
    int* deg_out  = (int*)alloc((size_t)N0 * 4);
    int* cur_src  = (int*)alloc((size_t)NEDGE * 4);
    int* cur_dst  = (int*)alloc((size_t)NEDGE * 4);
    int* csr_src  = (int*)alloc((size_t)NEDGE * 4);
    int* csr_ptr  = (int*)alloc((size_t)(N0 + 1) * 4);
    int* fill     = (int*)alloc((size_t)N0 * 4);
    int* newid    = (int*)alloc((size_t)N0 * 4);
    int* oldid    = (int*)alloc((size_t)25000 * 4);
    float* garr   = (float*)alloc((size_t)25000 * 4);
    float* maxbuf = (float*)alloc(128 * 4);
    float* finalv = (float*)alloc(256 * 4);
    float* f1raw  = (float*)alloc(256 * 4);
    float* f2v    = (float*)alloc(128 * 4);
    int* ctrl     = (int*)alloc(64 * 4);
    int* gbins    = (int*)alloc(256 * 4);
    int* pcnt     = (int*)alloc(BMAX * 4);
    int* poff     = (int*)alloc(BMAX * 4);
    int* cntG     = (int*)alloc(BMAX * 4);
    int* cntE     = (int*)alloc(BMAX * 4);
    int* coffG    = (int*)alloc(BMAX * 4);
    int* coffE    = (int*)alloc(BMAX * 4);

    const int nb[3] = {50000, 25000, 12500};
    const int kb[3] = {25000, 12500, 6250};

    k_init<<<(NEDGE + 255) / 256, 256, 0, stream>>>(src, dst, cur_src, cur_dst, finalv, f1raw);

    for (int b = 0; b < 3; ++b) {
        int n = nb[b], k = kb[b];
        int B = (n + 1023) / 1024;
        k_zero<<<(n + 255) / 256, 256, 0, stream>>>(deg_in, deg_out, fill, n);
        k_hist<<<(NEDGE + 255) / 256, 256, 0, stream>>>(cur_src, cur_dst, deg_in, deg_out);
        k_norms<<<(n + 255) / 256, 256, 0, stream>>>(deg_in, deg_out, nsv, ndv, n);
        k_pcnt<<<B, 1024, 0, stream>>>(deg_in, pcnt, n);
        k_pscan<<<1, 64, 0, stream>>>(pcnt, poff, csr_ptr, n, B);
        k_pemit<<<B, 1024, 0, stream>>>(deg_in, poff, csr_ptr, n);
        k_fill<<<(NEDGE + 255) / 256, 256, 0, stream>>>(cur_src, cur_dst, csr_ptr, fill, csr_src);
        k_gemm<<<(n + 63) / 64, 256, 0, stream>>>(feat, buf1, oldid, garr, cW[b], buf0, n,
                                                  (b == 0) ? 0 : 1);
        k_agg_conv<<<(n + 3) / 4, 256, 0, stream>>>(buf0, csr_ptr, csr_src, nsv, ndv, cb[b],
                                                    sW[b], buf1, hs, n);
        k_agg_score<<<(n + 255) / 256, 256, 0, stream>>>(hs, csr_ptr, csr_src, nsv, ndv, sb[b],
                                                         score, n);
        k_rzero<<<1, 256, 0, stream>>>(gbins, ctrl);
        for (int pass = 0; pass < 4; ++pass) {
            k_rhist<<<128, 256, 0, stream>>>(score, ctrl, n, pass, gbins);
            k_rpick<<<1, 256, 0, stream>>>(pass, k, ctrl, gbins);
        }
        k_ccnt<<<B, 1024, 0, stream>>>(score, ctrl, n, cntG, cntE);
        k_cscan<<<1, 256, 0, stream>>>(cntG, cntE, coffG, coffE, B, maxbuf);
        k_cemit<<<B, 1024, 0, stream>>>(score, ctrl, coffG, coffE, n, newid, oldid, garr);
        k_fixup<<<(k + 255) / 256, 256, 0, stream>>>(oldid, garr, k, n);
        k_readout<<<256, 128, 0, stream>>>(buf1, oldid, garr, finalv, maxbuf, k, 1.0f / (float)k);
        k_finish<<<1, 128, 0, stream>>>(finalv, maxbuf);
        if (b < 2) k_remap<<<(NEDGE + 255) / 256, 256, 0, stream>>>(newid, cur_src, cur_dst);
    }

    k_mlp1<<<10, 256, 0, stream>>>(finalv, seq, lin1W, f1raw);
    k_mlp2<<<1, 128, 0, stream>>>(f1raw, lin1b, lin2W, lin2b, f2v);
    k_mlp3<<<16, 128, 0, stream>>>(f2v, lin3W, lin3b, out);
}